// Round 7
// baseline (271.957 us; speedup 1.0000x reference)
//
#include <hip/hip_runtime.h>
#include <math.h>

// DilatedAttention on MI355X (gfx950), bf16 MFMA implementation.
// L=4096, E=1024, H=16, D=64. Branches (sl,dr) = (1024,1),(2048,2),(4096,4).
// Every branch reduces to causal attention over g=1024 sparse positions.
//
// Attention in transposed-S form (S^T = K Q^T, O^T = V^T P^T), XOR-swizzled
// LDS tiles. R7: each wave processes TWO q-column groups (32 q / wave,
// 128 q rows / 4-wave block) -> half the iterations, K/V LDS frags reused
// across groups; double-buffered LDS with ONE barrier per iteration
// (write next buffer while computing current); register prefetch staging.

#define L_SEQ 4096
#define EDIM  1024
#define NH    16
#define HD    64
#define GLEN  1024

typedef __bf16 bf16;
typedef __bf16 bf16x8 __attribute__((ext_vector_type(8)));
typedef __bf16 bf16x4 __attribute__((ext_vector_type(4)));
typedef short  s16x4  __attribute__((ext_vector_type(4)));
typedef float  f32x4  __attribute__((ext_vector_type(4)));

// async global->LDS, 16B per lane (used by the GEMMs).
__device__ __forceinline__ void gload16(const bf16* g, bf16* l) {
  __builtin_amdgcn_global_load_lds(
      (__attribute__((address_space(1))) void*)(const_cast<bf16*>(g)),
      (__attribute__((address_space(3))) void*)(l),
      16, 0, 0);
}

// v_mfma_f32_16x16x16_bf16 (builtin name only exists in the device pass).
__device__ __forceinline__ f32x4 mfma16x16x16_bf16(bf16x4 a, bf16x4 b, f32x4 c) {
#if defined(__HIP_DEVICE_COMPILE__)
  union { bf16x4 h; s16x4 s; } ua, ub;
  ua.h = a; ub.h = b;
  return __builtin_amdgcn_mfma_f32_16x16x16bf16_1k(ua.s, ub.s, c, 0, 0, 0);
#else
  (void)a; (void)b;
  return c;   // host stub, never executed
#endif
}

// ---------------------------------------------------------------------------
// fp32 -> bf16 conversion for query/key/value (L*E) and Wq/Wk/Wv/Wo (E*E)
// ---------------------------------------------------------------------------
__global__ __launch_bounds__(256) void cvt_kernel(
    const float* q, const float* k, const float* v,
    const float* wq, const float* wk, const float* wv, const float* wo,
    bf16* oq, bf16* ok, bf16* ov,
    bf16* owq, bf16* owk, bf16* owv, bf16* owo)
{
  const float* src; bf16* dst; int n;
  switch (blockIdx.y) {
    case 0: src = q;  dst = oq;  n = L_SEQ*EDIM; break;
    case 1: src = k;  dst = ok;  n = L_SEQ*EDIM; break;
    case 2: src = v;  dst = ov;  n = L_SEQ*EDIM; break;
    case 3: src = wq; dst = owq; n = EDIM*EDIM; break;
    case 4: src = wk; dst = owk; n = EDIM*EDIM; break;
    case 5: src = wv; dst = owv; n = EDIM*EDIM; break;
    default: src = wo; dst = owo; n = EDIM*EDIM; break;
  }
  int i = (blockIdx.x * 256 + threadIdx.x) * 8;
  if (i >= n) return;
  const float4* s4 = (const float4*)(src + i);
  float4 a = s4[0], b = s4[1];
  bf16x8 o = { (bf16)a.x, (bf16)a.y, (bf16)a.z, (bf16)a.w,
               (bf16)b.x, (bf16)b.y, (bf16)b.z, (bf16)b.w };
  *(bf16x8*)(dst + i) = o;
}

// ---------------------------------------------------------------------------
// GEMM: C[m][n] = sum_k A[m][k] * W[n][k] + bias[n]   (B^T layout)
// ---------------------------------------------------------------------------
template <typename OutT>
__device__ __forceinline__ void gemm_body(const bf16* __restrict__ A,
                                          const bf16* __restrict__ W,
                                          const float* __restrict__ bias,
                                          OutT* __restrict__ C)
{
  constexpr int K = 1024;
  __shared__ __align__(16) bf16 lA[128 * 32];
  __shared__ __align__(16) bf16 lB[128 * 32];

  const int tid  = threadIdx.x;
  const int lane = tid & 63;
  const int w    = tid >> 6;
  const int quad = lane >> 4;
  const int l16  = lane & 15;
  const int wr   = w >> 1, wc = w & 1;
  const int row0 = blockIdx.y * 128;
  const int col0 = blockIdx.x * 128;

  f32x4 acc[4][4] = {};

  const int c0 = tid, c1 = tid + 256;
  const bf16* Ab0 = A + (size_t)(row0 + (c0 >> 2)) * K + (c0 & 3) * 8;
  const bf16* Ab1 = A + (size_t)(row0 + (c1 >> 2)) * K + (c1 & 3) * 8;
  const bf16* Bb0 = W + (size_t)(col0 + (c0 >> 2)) * K + (c0 & 3) * 8;
  const bf16* Bb1 = W + (size_t)(col0 + (c1 >> 2)) * K + (c1 & 3) * 8;
  bf16* lA0 = &lA[c0 * 8]; bf16* lA1 = &lA[c1 * 8];
  bf16* lB0 = &lB[c0 * 8]; bf16* lB1 = &lB[c1 * 8];

  for (int kt = 0; kt < K; kt += 32) {
    __syncthreads();
    gload16(Ab0 + kt, lA0);
    gload16(Ab1 + kt, lA1);
    gload16(Bb0 + kt, lB0);
    gload16(Bb1 + kt, lB1);
    __syncthreads();

    bf16x8 af[4], bfrag[4];
#pragma unroll
    for (int mi = 0; mi < 4; mi++)
      af[mi] = *(const bf16x8*)&lA[(wr * 64 + mi * 16 + l16) * 32 + quad * 8];
#pragma unroll
    for (int ni = 0; ni < 4; ni++)
      bfrag[ni] = *(const bf16x8*)&lB[(wc * 64 + ni * 16 + l16) * 32 + quad * 8];
#pragma unroll
    for (int mi = 0; mi < 4; mi++)
#pragma unroll
      for (int ni = 0; ni < 4; ni++)
        acc[mi][ni] = __builtin_amdgcn_mfma_f32_16x16x32_bf16(
            af[mi], bfrag[ni], acc[mi][ni], 0, 0, 0);
  }

#pragma unroll
  for (int mi = 0; mi < 4; mi++) {
#pragma unroll
    for (int ni = 0; ni < 4; ni++) {
      const int gcol = col0 + wc * 64 + ni * 16 + l16;
      const float bv = bias[gcol];
#pragma unroll
      for (int r = 0; r < 4; r++) {
        const int grow = row0 + wr * 64 + mi * 16 + quad * 4 + r;
        C[(size_t)grow * 1024 + gcol] = (OutT)(acc[mi][ni][r] + bv);
      }
    }
  }
}

__global__ __launch_bounds__(256) void gemm_qkv_kernel(
    const bf16* xq, const bf16* xk, const bf16* xv,
    const bf16* wq, const bf16* wk, const bf16* wv,
    const float* bq, const float* bk, const float* bv,
    bf16* q, bf16* k, bf16* v)
{
  const bf16 *A, *W; const float* bias; bf16* C;
  if (blockIdx.z == 0)      { A = xq; W = wq; bias = bq; C = q; }
  else if (blockIdx.z == 1) { A = xk; W = wk; bias = bk; C = k; }
  else                      { A = xv; W = wv; bias = bv; C = v; }
  gemm_body<bf16>(A, W, bias, C);
}

__global__ __launch_bounds__(256) void gemm_out_kernel(
    const bf16* A, const bf16* W, const float* bias, float* C)
{
  gemm_body<float>(A, W, bias, C);
}

// ---------------------------------------------------------------------------
// K/V reshape into per-branch tile-contiguous sparse layouts:
//   kt_b[((seg*16+h)*16 + tile)*4096 + kj_local*64 + d]      (K as [kj][d])
//   vt_b[((seg*16+h)*16 + tile)*4096 + d*64 + kj_local]      (V^T as [d][kj])
// ---------------------------------------------------------------------------
__global__ __launch_bounds__(256) void reshape_kernel(
    const bf16* __restrict__ k, const bf16* __restrict__ v,
    bf16* kt0, bf16* kt1, bf16* kt2,
    bf16* vt0, bf16* vt1, bf16* vt2)
{
  __shared__ __align__(16) bf16 ltile[64 * 72];   // [kj][d], padded
  const int bid = blockIdx.x;
  int sl, dr, rem, shift; bf16 *ktb, *vtb;
  if (bid < 1024)      { sl = 1024; dr = 1; rem = bid;        ktb = kt0; vtb = vt0; shift = 4; }
  else if (bid < 1536) { sl = 2048; dr = 2; rem = bid - 1024; ktb = kt1; vtb = vt1; shift = 3; }
  else                 { sl = 4096; dr = 4; rem = bid - 1536; ktb = kt2; vtb = vt2; shift = 2; }
  const int ktile = rem & 15;
  const int h     = (rem >> 4) & 15;
  const int seg   = rem >> 8;
  const int grp   = h >> shift;          // h / (16/dr)
  const int segbase = seg * sl;
  const int tid = threadIdx.x;
  const size_t tOff = ((size_t)((seg * NH + h) * 16 + ktile)) * 4096;

  // K: straight gather, [kj][d] tile-contiguous
  {
#pragma unroll
    for (int half = 0; half < 2; half++) {
      const int p   = tid + half * 256;            // chunk 0..511
      const int kjl = p >> 3, dc = p & 7;
      const bf16* src = k + (size_t)(segbase + (ktile * 64 + kjl) * dr + grp) * EDIM + h * 64 + dc * 8;
      *(uint4*)(ktb + tOff + p * 8) = *(const uint4*)src;
    }
  }
  // V: gather into LDS, transpose, write [d][kj] tile-contiguous
  {
    const int i = tid >> 2, dc = tid & 3;
    const size_t p = (size_t)(segbase + (ktile * 64 + i) * dr + grp);
    const bf16* src = v + p * EDIM + h * 64 + dc * 16;
    *(uint4*)&ltile[i * 72 + dc * 16]     = *(const uint4*)(src);
    *(uint4*)&ltile[i * 72 + dc * 16 + 8] = *(const uint4*)(src + 8);
  }
  __syncthreads();
  {
    const int d = tid >> 2, kc = tid & 3;
    __align__(16) bf16 tmp[16];
#pragma unroll
    for (int j = 0; j < 16; j++) tmp[j] = ltile[(kc * 16 + j) * 72 + d];
    bf16* dst = vtb + tOff + d * 64 + kc * 16;
    *(uint4*)dst       = *(uint4*)&tmp[0];
    *(uint4*)(dst + 8) = *(uint4*)&tmp[8];
  }
}

// ---------------------------------------------------------------------------
// Flash attention, transposed-S, XOR-swizzled LDS, 2 q-groups per wave.
// Block = (branch, seg, h, qt2 of 8): q rows [qt2*128, qt2*128+128).
// Wave w, group g owns q rows qt2*128 + g*64 + w*16 + l16 (lane l16 = q col).
// k-tiles 0..2*qt2+1; group 0 diag at kt=2*qt2 (skips last tile), group 1
// diag at kt=2*qt2+1. Double-buffered LDS, ONE barrier/iter, reg prefetch.
// LDS swizzle: 16B chunk (row r, slot s) holds global chunk s^(r&7).
// ---------------------------------------------------------------------------
__global__ __launch_bounds__(256) void attn_kernel(
    const bf16* __restrict__ qg,
    const bf16* kt0, const bf16* kt1, const bf16* kt2,
    const bf16* vt0, const bf16* vt1, const bf16* vt2,
    bf16* o0, bf16* o1, bf16* o2,
    float* l0, float* l1, float* l2)
{
  __shared__ __align__(16) bf16 lK[2][64 * 64];
  __shared__ __align__(16) bf16 lV[2][64 * 64];

  const int bid = blockIdx.x;
  int sl, dr, rem, shift;
  const bf16 *ktb, *vtb; bf16* ob; float* lseb;
  if (bid < 512)       { sl = 1024; dr = 1; rem = bid;       ktb = kt0; vtb = vt0; ob = o0; lseb = l0; shift = 4; }
  else if (bid < 768)  { sl = 2048; dr = 2; rem = bid - 512; ktb = kt1; vtb = vt1; ob = o1; lseb = l1; shift = 3; }
  else                 { sl = 4096; dr = 4; rem = bid - 768; ktb = kt2; vtb = vt2; ob = o2; lseb = l2; shift = 2; }
  const int qt2 = 7 - (rem & 7);         // descending: long blocks first
  const int h   = (rem >> 3) & 15;
  const int seg = rem >> 7;
  const int grp = h >> shift;
  const int segbase = seg * sl;

  const int tid = threadIdx.x, lane = tid & 63, w = tid >> 6;
  const int quad = lane >> 4, l16 = lane & 15;
  const int ktd0 = 2 * qt2;              // group-0 diagonal k-tile
  const int ktmx = 2 * qt2 + 1;          // last k-tile (= group-1 diagonal)

  int qi[2];                             // per-group q row of this lane
  qi[0] = qt2 * 128 + w * 16 + l16;
  qi[1] = qi[0] + 64;

  // Q fragments: B[k=d][n=q=l16], two 32-k halves per group
  bf16x8 qa[2][2];
#pragma unroll
  for (int g = 0; g < 2; g++) {
    const size_t p = (size_t)(segbase + qi[g] * dr + grp);
    const bf16* qp = qg + p * EDIM + h * 64 + quad * 8;
    qa[g][0] = *(const bf16x8*)(qp);
    qa[g][1] = *(const bf16x8*)(qp + 32);
  }

  f32x4 Oa[2][4] = {};                   // O^T frags per group
  float m_r[2] = { -__builtin_inff(), -__builtin_inff() };
  float l_r[2] = { 0.f, 0.f };

  const bf16* kbase = ktb + ((size_t)((seg * NH + h) * 16)) * 4096;
  const bf16* vbase = vtb + ((size_t)((seg * NH + h) * 16)) * 4096;

  // staging chunks p0 = tid, p1 = tid+256; LDS slot: row r=p>>3, slot (p&7)^(r&7)
  const int p0 = tid, p1 = tid + 256;
  const int s0 = (p0 >> 3) * 64 + (((p0 & 7) ^ ((p0 >> 3) & 7)) * 8);
  const int s1 = (p1 >> 3) * 64 + (((p1 & 7) ^ ((p1 >> 3) & 7)) * 8);

  // prologue: tile 0 -> buf0; prefetch tile 1 -> regs
  uint4 rk0 = *(const uint4*)(kbase + p0 * 8);
  uint4 rk1 = *(const uint4*)(kbase + p1 * 8);
  uint4 rv0 = *(const uint4*)(vbase + p0 * 8);
  uint4 rv1 = *(const uint4*)(vbase + p1 * 8);
  *(uint4*)&lK[0][s0] = rk0;
  *(uint4*)&lK[0][s1] = rk1;
  *(uint4*)&lV[0][s0] = rv0;
  *(uint4*)&lV[0][s1] = rv1;
  {
    const bf16* kT = kbase + 4096;
    const bf16* vT = vbase + 4096;
    rk0 = *(const uint4*)(kT + p0 * 8);
    rk1 = *(const uint4*)(kT + p1 * 8);
    rv0 = *(const uint4*)(vT + p0 * 8);
    rv1 = *(const uint4*)(vT + p1 * 8);
  }

  for (int kt = 0; kt <= ktmx; kt++) {
    __syncthreads();                     // buf[kt&1] staged; no wave still in kt-1
    const bf16* bK = lK[kt & 1];
    const bf16* bV = lV[kt & 1];

    const bool last = (kt == ktmx);
    const int tK = last ? w : 3;         // K/V frags needed up to this t

    // ---- S^T = K Q^T for both groups, sharing K fragments ----
    f32x4 s[2][4];
    const bool act0 = (kt <= ktd0);
    const int tmax0 = (kt == ktd0) ? w : 3;
    const int tmax1 = last ? w : 3;
#pragma unroll
    for (int t = 0; t < 4; t++) {
      if (t <= tK) {
        const int kj = t * 16 + l16;
        const int rs = kj & 7;
        bf16x8 ka0 = *(const bf16x8*)&bK[kj * 64 + ((quad       ^ rs) * 8)];
        bf16x8 ka1 = *(const bf16x8*)&bK[kj * 64 + (((4 + quad) ^ rs) * 8)];
        if (act0 && t <= tmax0) {
          f32x4 z = {0.f, 0.f, 0.f, 0.f};
          z = __builtin_amdgcn_mfma_f32_16x16x32_bf16(ka0, qa[0][0], z, 0, 0, 0);
          s[0][t] = __builtin_amdgcn_mfma_f32_16x16x32_bf16(ka1, qa[0][1], z, 0, 0, 0);
        }
        {
          f32x4 z = {0.f, 0.f, 0.f, 0.f};
          z = __builtin_amdgcn_mfma_f32_16x16x32_bf16(ka0, qa[1][0], z, 0, 0, 0);
          s[1][t] = __builtin_amdgcn_mfma_f32_16x16x32_bf16(ka1, qa[1][1], z, 0, 0, 0);
        }
      }
    }

    // ---- online softmax per group ----
    bf16x4 pb[2][4];
#pragma unroll
    for (int g = 0; g < 2; g++) {
      const bool act  = (g == 0) ? act0 : true;
      if (!act) continue;                 // wave-uniform
      const bool diag = (kt == (g ? ktmx : ktd0));
      const int tmax  = (g == 0) ? tmax0 : tmax1;
      float p[4][4];
      float mloc = -__builtin_inff();
#pragma unroll
      for (int t = 0; t < 4; t++) {
        if (t <= tmax) {
#pragma unroll
          for (int r = 0; r < 4; r++) {
            float sv = s[g][t][r] * 0.125f;          // 1/sqrt(64)
            if (diag) {
              const int kj = kt * 64 + t * 16 + quad * 4 + r;
              if (kj > qi[g]) sv = -__builtin_inff();
            }
            p[t][r] = sv;
            mloc = fmaxf(mloc, sv);
          }
        }
      }
      mloc = fmaxf(mloc, __shfl_xor(mloc, 16, 64));
      mloc = fmaxf(mloc, __shfl_xor(mloc, 32, 64));
      const float mnew  = fmaxf(m_r[g], mloc);
      const float alpha = __expf(m_r[g] - mnew);
      m_r[g] = mnew;

      float rs_sum = 0.f;
#pragma unroll
      for (int t = 0; t < 4; t++) {
        if (t <= tmax) {
#pragma unroll
          for (int r = 0; r < 4; r++) {
            const float pv = __expf(p[t][r] - mnew);
            pb[g][t][r] = (bf16)pv;
            rs_sum += pv;
          }
        }
      }
      rs_sum += __shfl_xor(rs_sum, 16, 64);
      rs_sum += __shfl_xor(rs_sum, 32, 64);
      l_r[g] = l_r[g] * alpha + rs_sum;

#pragma unroll
      for (int nf = 0; nf < 4; nf++)
#pragma unroll
        for (int r = 0; r < 4; r++) Oa[g][nf][r] *= alpha;
    }

    // ---- O^T += V^T P^T, sharing V fragments across groups ----
#pragma unroll
    for (int t = 0; t < 4; t++) {
      if (t <= tK) {
        const int ck  = 2 * t + (quad >> 1);
        const int sub = (quad & 1) * 4;
#pragma unroll
        for (int nf = 0; nf < 4; nf++) {
          const int drow = nf * 16 + l16;
          bf16x4 va = *(const bf16x4*)&bV[drow * 64 + ((ck ^ (drow & 7)) * 8) + sub];
          if (act0 && t <= tmax0)
            Oa[0][nf] = mfma16x16x16_bf16(va, pb[0][t], Oa[0][nf]);
          if (t <= tmax1)
            Oa[1][nf] = mfma16x16x16_bf16(va, pb[1][t], Oa[1][nf]);
        }
      }
    }

    // ---- stage tile kt+1 into the other buffer; prefetch kt+2 ----
    if (kt < ktmx) {
      const int nb = (kt + 1) & 1;
      *(uint4*)&lK[nb][s0] = rk0;
      *(uint4*)&lK[nb][s1] = rk1;
      *(uint4*)&lV[nb][s0] = rv0;
      *(uint4*)&lV[nb][s1] = rv1;
      if (kt + 1 < ktmx) {
        const bf16* kT = kbase + (size_t)(kt + 2) * 4096;
        const bf16* vT = vbase + (size_t)(kt + 2) * 4096;
        rk0 = *(const uint4*)(kT + p0 * 8);
        rk1 = *(const uint4*)(kT + p1 * 8);
        rv0 = *(const uint4*)(vT + p0 * 8);
        rv1 = *(const uint4*)(vT + p1 * 8);
      }
    }
  }

  // epilogue: both groups; d = nf*16 + quad*4 + r
#pragma unroll
  for (int g = 0; g < 2; g++) {
    const float linv = 1.0f / l_r[g];
    const int pdense = segbase + qi[g] * dr + grp;
    bf16* orow = ob + (size_t)pdense * EDIM + h * 64;
#pragma unroll
    for (int nf = 0; nf < 4; nf++) {
      bf16x4 ov;
#pragma unroll
      for (int r = 0; r < 4; r++) ov[r] = (bf16)(Oa[g][nf][r] * linv);
      *(bf16x4*)(orow + nf * 16 + quad * 4) = ov;
    }
    if (quad == 0)
      lseb[h * L_SEQ + pdense] = m_r[g] + __logf(l_r[g]);
  }
}

// ---------------------------------------------------------------------------
// Merge: softmax over branch lse at each (h,p); coverage computed analytically.
// ---------------------------------------------------------------------------
__global__ __launch_bounds__(256) void merge_kernel(
    const bf16* __restrict__ o0, const bf16* __restrict__ o1, const bf16* __restrict__ o2,
    const float* __restrict__ l0, const float* __restrict__ l1, const float* __restrict__ l2,
    bf16* __restrict__ merged)
{
  const int idx = blockIdx.x * 256 + threadIdx.x;   // over L*H*8
  const int dc = idx & 7;
  const int h  = (idx >> 3) & 15;
  const int p  = idx >> 7;
  const bool c1 = ((p & 1) == (h >> 3));   // branch dr=2 coverage
  const bool c2 = ((p & 3) == (h >> 2));   // branch dr=4 coverage
  const float s0 = l0[h * L_SEQ + p];
  const float s1 = c1 ? l1[h * L_SEQ + p] : -__builtin_inff();
  const float s2 = c2 ? l2[h * L_SEQ + p] : -__builtin_inff();
  const float mx = fmaxf(s0, fmaxf(s1, s2));
  float w0 = __expf(s0 - mx);
  float w1 = c1 ? __expf(s1 - mx) : 0.f;
  float w2 = c2 ? __expf(s2 - mx) : 0.f;
  const float inv = 1.0f / (w0 + w1 + w2);
  w0 *= inv; w1 *= inv; w2 *= inv;

  const size_t off = (size_t)p * EDIM + h * 64 + dc * 8;
  float acc[8];
  bf16x8 a0 = *(const bf16x8*)(o0 + off);
#pragma unroll
  for (int j = 0; j < 8; j++) acc[j] = w0 * (float)a0[j];
  if (c1) {
    bf16x8 a1 = *(const bf16x8*)(o1 + off);
#pragma unroll
    for (int j = 0; j < 8; j++) acc[j] += w1 * (float)a1[j];
  }
  if (c2) {
    bf16x8 a2 = *(const bf16x8*)(o2 + off);
#pragma unroll
    for (int j = 0; j < 8; j++) acc[j] += w2 * (float)a2[j];
  }
  bf16x8 r;
#pragma unroll
  for (int j = 0; j < 8; j++) r[j] = (bf16)acc[j];
  *(bf16x8*)(merged + off) = r;
}

// ---------------------------------------------------------------------------
extern "C" void kernel_launch(void* const* d_in, const int* in_sizes, int n_in,
                              void* d_out, int out_size, void* d_ws, size_t ws_size,
                              hipStream_t stream)
{
  (void)in_sizes; (void)n_in; (void)out_size; (void)ws_size;
  const float* query = (const float*)d_in[0];
  const float* key   = (const float*)d_in[1];
  const float* value = (const float*)d_in[2];
  const float* Wq = (const float*)d_in[3];
  const float* bq = (const float*)d_in[4];
  const float* Wk = (const float*)d_in[5];
  const float* bk = (const float*)d_in[6];
  const float* Wv = (const float*)d_in[7];
  const float* bv = (const float*)d_in[8];
  const float* Wo = (const float*)d_in[9];
  const float* bo = (const float*)d_in[10];

  char* base = (char*)d_ws;
  size_t off = 0;
  auto take = [&](size_t nbytes) -> char* {
    char* p = base + off;
    off += (nbytes + 255) & ~(size_t)255;
    return p;
  };
  const size_t LE2 = (size_t)L_SEQ * EDIM * 2;
  const size_t EE2 = (size_t)EDIM * EDIM * 2;
  bf16* xq  = (bf16*)take(LE2);
  bf16* xk  = (bf16*)take(LE2);
  bf16* xv  = (bf16*)take(LE2);
  bf16* wqb = (bf16*)take(EE2);
  bf16* wkb = (bf16*)take(EE2);
  bf16* wvb = (bf16*)take(EE2);
  bf16* wob = (bf16*)take(EE2);
  bf16* qb  = (bf16*)take(LE2);
  bf16* kb  = (bf16*)take(LE2);
  bf16* vb  = (bf16*)take(LE2);
  bf16* kt0 = (bf16*)take((size_t)4 * NH * GLEN * HD * 2);
  bf16* kt1 = (bf16*)take((size_t)2 * NH * GLEN * HD * 2);
  bf16* kt2 = (bf16*)take((size_t)1 * NH * GLEN * HD * 2);
  bf16* vt0 = (bf16*)take((size_t)4 * NH * HD * GLEN * 2);
  bf16* vt1 = (bf16*)take((size_t)2 * NH * HD * GLEN * 2);
  bf16* vt2 = (bf16*)take((size_t)1 * NH * HD * GLEN * 2);
  float* lse0 = (float*)take((size_t)NH * L_SEQ * 4);
  float* lse1 = (float*)take((size_t)NH * L_SEQ * 4);
  float* lse2 = (float*)take((size_t)NH * L_SEQ * 4);
  bf16* merged = (bf16*)take(LE2);
  // branch outputs alias the converted inputs (dead after gemm_qkv)
  bf16* o0 = xq; bf16* o1 = xk; bf16* o2 = xv;

  dim3 blk(256);
  cvt_kernel<<<dim3(2048, 7), blk, 0, stream>>>(
      query, key, value, Wq, Wk, Wv, Wo, xq, xk, xv, wqb, wkb, wvb, wob);
  gemm_qkv_kernel<<<dim3(8, 32, 3), blk, 0, stream>>>(
      xq, xk, xv, wqb, wkb, wvb, bq, bk, bv, qb, kb, vb);
  reshape_kernel<<<dim3(1792), blk, 0, stream>>>(
      kb, vb, kt0, kt1, kt2, vt0, vt1, vt2);
  attn_kernel<<<dim3(896), blk, 0, stream>>>(
      qb, kt0, kt1, kt2, vt0, vt1, vt2, o0, o1, o2, lse0, lse1, lse2);
  merge_kernel<<<dim3(2048), blk, 0, stream>>>(
      o0, o1, o2, lse0, lse1, lse2, merged);
  gemm_out_kernel<<<dim3(8, 32), blk, 0, stream>>>(merged, wob, bo, (float*)d_out);
}